// Round 1
// baseline (335.137 us; speedup 1.0000x reference)
//
#include <hip/hip_runtime.h>

#define N1 8192
#define N2 8192
#define DIM 256
#define TILE 128
#define BK 32

typedef _Float16 half8 __attribute__((ext_vector_type(8)));
typedef float f32x4 __attribute__((ext_vector_type(4)));

// Async global->LDS, 16B per lane. LDS dest is wave-uniform base + lane*16.
__device__ __forceinline__ void async_load16(const void* g, void* lds) {
    __builtin_amdgcn_global_load_lds(
        (__attribute__((address_space(1))) void*)g,
        (__attribute__((address_space(3))) void*)lds,
        16, 0, 0);
}

// --- Kernel 1: column mean of x1 (adj must be pre-zeroed) ---
__global__ __launch_bounds__(256) void colmean_kernel(const float* __restrict__ x1,
                                                      float* __restrict__ adj) {
    int t = threadIdx.x;                 // dim index 0..255
    size_t r0 = (size_t)blockIdx.x * 64; // 64 rows per block
    float s = 0.f;
    #pragma unroll 4
    for (int r = 0; r < 64; ++r) s += x1[(r0 + r) * DIM + t];
    atomicAdd(&adj[t], s * (1.0f / (float)N1));
}

// --- Kernel 2: center, scale, quantize to fp16; row sq-norms from quantized values ---
__global__ __launch_bounds__(256) void quant_kernel(
    const float* __restrict__ x1, const float* __restrict__ x2,
    const float* __restrict__ adj, const float* __restrict__ ls,
    _Float16* __restrict__ y1, _Float16* __restrict__ y2,
    float* __restrict__ sq1, float* __restrict__ sq2) {
    int b = blockIdx.x;
    const float* x; _Float16* y; float* sq; int row;
    if (b < N1) { x = x1; y = y1; sq = sq1; row = b; }
    else        { x = x2; y = y2; sq = sq2; row = b - N1; }
    int t = threadIdx.x;
    float v = (x[(size_t)row * DIM + t] - adj[t]) / ls[t];
    _Float16 h = (_Float16)v;
    y[(size_t)row * DIM + t] = h;
    float hv = (float)h;
    float p = hv * hv;
    #pragma unroll
    for (int off = 32; off > 0; off >>= 1) p += __shfl_down(p, off, 64);
    __shared__ float red[4];
    if ((t & 63) == 0) red[t >> 6] = p;
    __syncthreads();
    if (t == 0) sq[row] = red[0] + red[1] + red[2] + red[3];
}

// --- Kernel 3: 128x128 tile MFMA GEMM (A*B^T form) + fused Matern epilogue ---
__global__ __launch_bounds__(256) void matern_gemm(
    const _Float16* __restrict__ y1, const _Float16* __restrict__ y2,
    const float* __restrict__ sq1, const float* __restrict__ sq2,
    float* __restrict__ out) {
    // Unpadded row-major [128][32] fp16 tiles (layout forced by global_load_lds
    // lane-contiguity: lds addr = base + lane*16).
    __shared__ __align__(16) _Float16 As[TILE * BK];
    __shared__ __align__(16) _Float16 Bs[TILE * BK];

    const int tid  = threadIdx.x;
    const int wave = tid >> 6;
    const int lane = tid & 63;
    const int row0 = blockIdx.x * TILE;  // M offset (x1 rows)
    const int col0 = blockIdx.y * TILE;  // N offset (x2 rows)
    // 2x2 wave grid; each wave owns a 64x64 sub-tile = 4x4 MFMA tiles of 16x16
    const int wm = (wave >> 1) * 64;
    const int wn = (wave & 1) * 64;
    // fragment read coords: A[m=lane&15][k=(lane>>4)*8+j] (B identical, B^T input)
    const int fm = lane & 15;
    const int fk = (lane >> 4) * 8;

    f32x4 acc[4][4];
    const f32x4 zero = {0.f, 0.f, 0.f, 0.f};
    #pragma unroll
    for (int i = 0; i < 4; ++i)
        #pragma unroll
        for (int j = 0; j < 4; ++j) acc[i][j] = zero;

    // staging: 512 16B-chunks per tile, 2 per thread; chunk c -> row c>>2, k (c&3)*8
    const int c0 = wave * 128 + lane;
    const int c1 = wave * 128 + 64 + lane;
    const int r0c = c0 >> 2, k0c = (c0 & 3) * 8;
    const int r1c = c1 >> 2, k1c = (c1 & 3) * 8;
    char* ldsA = (char*)As;
    char* ldsB = (char*)Bs;
    const int base0 = (wave * 128) * 16;       // wave-uniform LDS byte base, q=0
    const int base1 = (wave * 128 + 64) * 16;  // q=1

    for (int kt = 0; kt < DIM; kt += BK) {
        __syncthreads();  // previous iter's LDS reads done before overwrite
        async_load16(y1 + (size_t)(row0 + r0c) * DIM + kt + k0c, ldsA + base0);
        async_load16(y1 + (size_t)(row0 + r1c) * DIM + kt + k1c, ldsA + base1);
        async_load16(y2 + (size_t)(col0 + r0c) * DIM + kt + k0c, ldsB + base0);
        async_load16(y2 + (size_t)(col0 + r1c) * DIM + kt + k1c, ldsB + base1);
        __syncthreads();  // drains vmcnt: staged data visible

        half8 a[4], b[4];
        #pragma unroll
        for (int t = 0; t < 4; ++t)
            a[t] = *(const half8*)&As[(wm + t * 16 + fm) * BK + fk];
        #pragma unroll
        for (int t = 0; t < 4; ++t)
            b[t] = *(const half8*)&Bs[(wn + t * 16 + fm) * BK + fk];
        #pragma unroll
        for (int i = 0; i < 4; ++i)
            #pragma unroll
            for (int j = 0; j < 4; ++j)
                acc[i][j] = __builtin_amdgcn_mfma_f32_16x16x32_f16(a[i], b[j], acc[i][j], 0, 0, 0);
    }

    // Epilogue: C/D layout col=lane&15, row=(lane>>4)*4+reg (dtype-independent)
    const int erow = (lane >> 4) * 4;
    const int ecol = lane & 15;
    #pragma unroll
    for (int i = 0; i < 4; ++i) {
        #pragma unroll
        for (int j = 0; j < 4; ++j) {
            #pragma unroll
            for (int r = 0; r < 4; ++r) {
                int gi = row0 + wm + i * 16 + erow + r;
                int gj = col0 + wn + j * 16 + ecol;
                float d2 = sq1[gi] + sq2[gj] - 2.0f * acc[i][j][r];
                d2 = fmaxf(d2, 0.0f);
                float dist = sqrtf(d2);
                dist = fmaxf(dist, 1e-15f);
                float t3 = 1.7320508075688772f * dist;
                out[(size_t)gi * N2 + gj] = (1.0f + t3) * __expf(-t3);
            }
        }
    }
}

extern "C" void kernel_launch(void* const* d_in, const int* in_sizes, int n_in,
                              void* d_out, int out_size, void* d_ws, size_t ws_size,
                              hipStream_t stream) {
    const float* x1 = (const float*)d_in[0];
    const float* x2 = (const float*)d_in[1];
    const float* ls = (const float*)d_in[2];
    float* out = (float*)d_out;

    // workspace layout: adj[256]f32 | sq1[8192]f32 | sq2[8192]f32 | y1 fp16 4MB | y2 fp16 4MB
    char* ws = (char*)d_ws;
    float* adj = (float*)ws;                               // 1024 B
    float* sq1 = (float*)(ws + 1024);                      // 32 KB
    float* sq2 = (float*)(ws + 1024 + 32768);              // 32 KB
    _Float16* y1 = (_Float16*)(ws + 66560);                // 4 MB (16B aligned)
    _Float16* y2 = (_Float16*)(ws + 66560 + 4194304);      // 4 MB

    hipMemsetAsync(adj, 0, 256 * sizeof(float), stream);
    colmean_kernel<<<N1 / 64, 256, 0, stream>>>(x1, adj);
    quant_kernel<<<N1 + N2, 256, 0, stream>>>(x1, x2, adj, ls, y1, y2, sq1, sq2);
    matern_gemm<<<dim3(N1 / TILE, N2 / TILE), 256, 0, stream>>>(y1, y2, sq1, sq2, out);
}

// Round 2
// 329.802 us; speedup vs baseline: 1.0162x; 1.0162x over previous
//
#include <hip/hip_runtime.h>

#define N1 8192
#define N2 8192
#define DIM 256
#define TILE 128
#define BK 32
#define KITERS (DIM / BK)   // 8

typedef _Float16 half8 __attribute__((ext_vector_type(8)));
typedef _Float16 half4v __attribute__((ext_vector_type(4)));
typedef float f32x4 __attribute__((ext_vector_type(4)));

// Async global->LDS, 16B per lane. LDS dest is wave-uniform base + lane*16.
__device__ __forceinline__ void async_load16(const void* g, void* lds) {
    __builtin_amdgcn_global_load_lds(
        (__attribute__((address_space(1))) void*)g,
        (__attribute__((address_space(3))) void*)lds,
        16, 0, 0);
}

// --- Kernel 1: column mean of x1 (adj pre-zeroed). 512 blocks x 16 rows. ---
__global__ __launch_bounds__(256) void colmean_kernel(const float* __restrict__ x1,
                                                      float* __restrict__ adj) {
    int t = threadIdx.x;                  // dim index 0..255 (coalesced per row)
    size_t r0 = (size_t)blockIdx.x * 16;
    float s = 0.f;
    #pragma unroll
    for (int r = 0; r < 16; ++r) s += x1[(r0 + r) * DIM + t];
    atomicAdd(&adj[t], s * (1.0f / (float)N1));
}

// --- Kernel 2: center/scale/quantize to fp16 + row sq-norms. One wave per row. ---
__global__ __launch_bounds__(256) void quant_kernel(
    const float* __restrict__ x1, const float* __restrict__ x2,
    const float* __restrict__ adj, const float* __restrict__ ls,
    _Float16* __restrict__ y1, _Float16* __restrict__ y2,
    float* __restrict__ sq1, float* __restrict__ sq2) {
    int wave = threadIdx.x >> 6, lane = threadIdx.x & 63;
    int grow = blockIdx.x * 4 + wave;
    const float* x; _Float16* y; float* sq; int row;
    if (grow < N1) { x = x1; y = y1; sq = sq1; row = grow; }
    else           { x = x2; y = y2; sq = sq2; row = grow - N1; }
    int c = lane * 4;
    f32x4 xv = *(const f32x4*)&x[(size_t)row * DIM + c];
    f32x4 av = *(const f32x4*)&adj[c];
    f32x4 lv = *(const f32x4*)&ls[c];
    half4v h;
    float p = 0.f;
    #pragma unroll
    for (int u = 0; u < 4; ++u) {
        float v = (xv[u] - av[u]) / lv[u];
        _Float16 hh = (_Float16)v;
        h[u] = hh;
        float f = (float)hh;
        p += f * f;
    }
    *(half4v*)&y[(size_t)row * DIM + c] = h;
    #pragma unroll
    for (int off = 32; off > 0; off >>= 1) p += __shfl_down(p, off, 64);
    if (lane == 0) sq[row] = p;
}

// --- Kernel 3: 128x128 tile MFMA GEMM, double-buffered LDS, fused Matern epilogue ---
__global__ __launch_bounds__(256) void matern_gemm(
    const _Float16* __restrict__ y1, const _Float16* __restrict__ y2,
    const float* __restrict__ sq1, const float* __restrict__ sq2,
    float* __restrict__ out) {
    // Unpadded row-major [128][32] fp16 tiles x2 buffers (layout forced by
    // global_load_lds lane-contiguity). 32 KB total.
    __shared__ __align__(16) _Float16 As[2][TILE * BK];
    __shared__ __align__(16) _Float16 Bs[2][TILE * BK];

    const int tid  = threadIdx.x;
    const int wave = tid >> 6;
    const int lane = tid & 63;
    const int row0 = blockIdx.x * TILE;  // M offset (x1 rows)
    const int col0 = blockIdx.y * TILE;  // N offset (x2 rows)
    const int wm = (wave >> 1) * 64;     // 2x2 wave grid, 64x64 per wave
    const int wn = (wave & 1) * 64;
    const int fm = lane & 15;            // A/B frag: [m][k] = [lane&15][(lane>>4)*8+j]
    const int fk = (lane >> 4) * 8;

    // staging: 512 16B-chunks per tile, 2 per thread; chunk c -> row c>>2, k (c&3)*8
    const int c0 = wave * 128 + lane;
    const int c1 = c0 + 64;
    const int r0c = c0 >> 2, k0c = (c0 & 3) * 8;
    const int r1c = c1 >> 2, k1c = (c1 & 3) * 8;
    const int base0 = (wave * 128) * 16;       // wave-uniform LDS byte base
    const int base1 = base0 + 64 * 16;

    f32x4 acc[4][4];
    const f32x4 zero = {0.f, 0.f, 0.f, 0.f};
    #pragma unroll
    for (int i = 0; i < 4; ++i)
        #pragma unroll
        for (int j = 0; j < 4; ++j) acc[i][j] = zero;

    auto stage = [&](int kt, int buf) {
        const int k = kt * BK;
        async_load16(y1 + (size_t)(row0 + r0c) * DIM + k + k0c, (char*)As[buf] + base0);
        async_load16(y1 + (size_t)(row0 + r1c) * DIM + k + k1c, (char*)As[buf] + base1);
        async_load16(y2 + (size_t)(col0 + r0c) * DIM + k + k0c, (char*)Bs[buf] + base0);
        async_load16(y2 + (size_t)(col0 + r1c) * DIM + k + k1c, (char*)Bs[buf] + base1);
    };

    stage(0, 0);
    int cur = 0;
    #pragma unroll
    for (int kt = 0; kt < KITERS; ++kt) {
        // Single barrier per iter: drains vmcnt (tile kt staged, issued one full
        // compute-phase ago) and fences iter kt-1's LDS reads.
        __syncthreads();
        if (kt + 1 < KITERS) stage(kt + 1, cur ^ 1);

        half8 a[4], b[4];
        #pragma unroll
        for (int t = 0; t < 4; ++t)
            a[t] = *(const half8*)&As[cur][(wm + t * 16 + fm) * BK + fk];
        #pragma unroll
        for (int t = 0; t < 4; ++t)
            b[t] = *(const half8*)&Bs[cur][(wn + t * 16 + fm) * BK + fk];
        #pragma unroll
        for (int i = 0; i < 4; ++i)
            #pragma unroll
            for (int j = 0; j < 4; ++j)
                acc[i][j] = __builtin_amdgcn_mfma_f32_16x16x32_f16(a[i], b[j], acc[i][j], 0, 0, 0);
        cur ^= 1;
    }

    // Epilogue: C/D layout col=lane&15, row=(lane>>4)*4+reg
    const int erow = (lane >> 4) * 4;
    const int ecol = lane & 15;
    float s1v[4][4];
    #pragma unroll
    for (int i = 0; i < 4; ++i)
        #pragma unroll
        for (int r = 0; r < 4; ++r)
            s1v[i][r] = sq1[row0 + wm + i * 16 + erow + r];
    float s2v[4];
    #pragma unroll
    for (int j = 0; j < 4; ++j)
        s2v[j] = sq2[col0 + wn + j * 16 + ecol];

    float* obase = out + (size_t)(row0 + wm + erow) * N2 + (col0 + wn + ecol);
    #pragma unroll
    for (int i = 0; i < 4; ++i) {
        #pragma unroll
        for (int r = 0; r < 4; ++r) {
            float* rowp = obase + (size_t)(i * 16 + r) * N2;  // stores use imm offsets j*64B
            #pragma unroll
            for (int j = 0; j < 4; ++j) {
                float d2 = s1v[i][r] + s2v[j] - 2.0f * acc[i][j][r];
                d2 = fmaxf(d2, 0.0f);
                float dist = fmaxf(sqrtf(d2), 1e-15f);
                float t3 = 1.7320508075688772f * dist;
                rowp[j * 16] = (1.0f + t3) * __expf(-t3);
            }
        }
    }
}

extern "C" void kernel_launch(void* const* d_in, const int* in_sizes, int n_in,
                              void* d_out, int out_size, void* d_ws, size_t ws_size,
                              hipStream_t stream) {
    const float* x1 = (const float*)d_in[0];
    const float* x2 = (const float*)d_in[1];
    const float* ls = (const float*)d_in[2];
    float* out = (float*)d_out;

    // workspace: adj[256]f32 | sq1[8192]f32 | sq2[8192]f32 | y1 fp16 4MB | y2 fp16 4MB
    char* ws = (char*)d_ws;
    float* adj = (float*)ws;
    float* sq1 = (float*)(ws + 1024);
    float* sq2 = (float*)(ws + 1024 + 32768);
    _Float16* y1 = (_Float16*)(ws + 66560);
    _Float16* y2 = (_Float16*)(ws + 66560 + 4194304);

    hipMemsetAsync(adj, 0, 256 * sizeof(float), stream);
    colmean_kernel<<<N1 / 16, 256, 0, stream>>>(x1, adj);
    quant_kernel<<<(N1 + N2) / 4, 256, 0, stream>>>(x1, x2, adj, ls, y1, y2, sq1, sq2);
    matern_gemm<<<dim3(N1 / TILE, N2 / TILE), 256, 0, stream>>>(y1, y2, sq1, sq2, out);
}